// Round 9
// baseline (202.988 us; speedup 1.0000x reference)
//
#include <hip/hip_runtime.h>
#include <cstdint>

typedef float v4f __attribute__((ext_vector_type(4)));
typedef unsigned int u32;
typedef unsigned long long u64;

#define N_PRED 8192
#define N_GT   32768
#define HOFF   64.0f        // h = p.q - 0.5|q|^2 + 64 > 0 always
#define NBIN   512

#define GT_TPS 128          // gt tile size
#define GT_NT  256          // gt tiles
#define PR_TPS 128          // pred tile size (rep targets)
#define PR_NT  64
#define CHN    256          // preds per chunk
#define NCH    32

// ---- ws layout (bytes) ----
#define O_GTCNT   0u            // u32[512]
#define O_PRCNT   2048u         // u32[512]
#define O_GTCUR   4096u         // u32[512]
#define O_PRCUR   6144u         // u32[512]
#define O_UBCNN   8192u         // u32[32]  chunk max ubNN (float bits)
#define O_UBCRP   8320u         // u32[32]  chunk max ubRep
#define O_KEYS    8448u         // u64[8192]
#define O_REPMX   73984u        // u32[8192]
#define MEMSET_BYTES 106752u    // everything above zeroed each launch
#define O_GTSTART 106752u       // u32[513]
#define O_PRSTART 108816u       // u32[513]
#define O_SGT     110880u       // v4f[32768] (x,y,z, 64-0.5|g|^2)
#define O_SGTIDX  635168u       // u32[32768]
#define O_SPR     766240u       // v4f[8192]
#define O_SPRIDX  897312u       // u32[8192]
#define O_UBNN    930080u       // f32[8192]
#define O_UBREP   962848u       // f32[8192]
#define O_GTTMIN  995616u       // f32[256]
#define O_GTTMAX  996640u       // f32[256]
#define O_PRTMIN  997664u       // f32[64]
#define O_PRTMAX  997920u       // f32[64]
#define O_PCMIN   998176u       // f32[32]
#define O_PCMAX   998304u       // f32[32]
#define O_PART    998432u       // f32[32*3]

__device__ __forceinline__ int zbin(float z) {
    int b = (int)((z + 4.0f) * 64.0f);
    return b < 0 ? 0 : (b > NBIN - 1 ? NBIN - 1 : b);
}

// ---- count: histogram z into 512 bins ----
__global__ __launch_bounds__(256) void k_count(const float* __restrict__ pred,
                                               const float* __restrict__ gt,
                                               u32* __restrict__ gtCount,
                                               u32* __restrict__ prCount) {
    const int i = blockIdx.x * 256 + threadIdx.x;
    if (i < N_GT) atomicAdd(&gtCount[zbin(gt[i * 6 + 2])], 1u);
    if (i < N_PRED) atomicAdd(&prCount[zbin(pred[i * 6 + 2])], 1u);
}

// ---- scan: exclusive prefix sums -> starts & cursors ----
__global__ __launch_bounds__(512) void k_scan(const u32* __restrict__ gtCount,
                                              const u32* __restrict__ prCount,
                                              u32* __restrict__ gtStart, u32* __restrict__ prStart,
                                              u32* __restrict__ gtCursor, u32* __restrict__ prCursor) {
    __shared__ u32 tmp[NBIN];
    const int tid = threadIdx.x;
    tmp[tid] = gtCount[tid];
    __syncthreads();
    for (int off = 1; off < NBIN; off <<= 1) {
        u32 add = (tid >= off) ? tmp[tid - off] : 0u;
        __syncthreads();
        tmp[tid] += add;
        __syncthreads();
    }
    u32 ex = tmp[tid] - gtCount[tid];
    gtStart[tid] = ex; gtCursor[tid] = ex;
    __syncthreads();
    tmp[tid] = prCount[tid];
    __syncthreads();
    for (int off = 1; off < NBIN; off <<= 1) {
        u32 add = (tid >= off) ? tmp[tid - off] : 0u;
        __syncthreads();
        tmp[tid] += add;
        __syncthreads();
    }
    ex = tmp[tid] - prCount[tid];
    prStart[tid] = ex; prCursor[tid] = ex;
}

// ---- scatter: bin-sorted arrays with packed w ----
__global__ __launch_bounds__(256) void k_scatter(const float* __restrict__ pred,
                                                 const float* __restrict__ gt,
                                                 u32* __restrict__ gtCursor, u32* __restrict__ prCursor,
                                                 v4f* __restrict__ sGt, u32* __restrict__ sGtIdx,
                                                 v4f* __restrict__ sPr, u32* __restrict__ sPrIdx) {
    const int i = blockIdx.x * 256 + threadIdx.x;
    if (i < N_GT) {
        const float x = gt[i * 6 + 0], y = gt[i * 6 + 1], z = gt[i * 6 + 2];
        const u32 pos = atomicAdd(&gtCursor[zbin(z)], 1u);
        v4f v; v.x = x; v.y = y; v.z = z;
        v.w = fmaf(-0.5f, fmaf(z, z, fmaf(y, y, x * x)), HOFF);
        sGt[pos] = v; sGtIdx[pos] = (u32)i;
    }
    if (i < N_PRED) {
        const float x = pred[i * 6 + 0], y = pred[i * 6 + 1], z = pred[i * 6 + 2];
        const u32 pos = atomicAdd(&prCursor[zbin(z)], 1u);
        v4f v; v.x = x; v.y = y; v.z = z;
        v.w = fmaf(-0.5f, fmaf(z, z, fmaf(y, y, x * x)), HOFF);
        sPr[pos] = v; sPrIdx[pos] = (u32)i;
    }
}

// ---- mid: tile/chunk z-bounds + phase A (upper bounds + seed keys) ----
__global__ __launch_bounds__(256) void k_mid(const v4f* __restrict__ sGt,
                                             const v4f* __restrict__ sPr,
                                             const u32* __restrict__ gtStart,
                                             const u32* __restrict__ prStart,
                                             float* __restrict__ gtTmin, float* __restrict__ gtTmax,
                                             float* __restrict__ prTmin, float* __restrict__ prTmax,
                                             float* __restrict__ pcMin, float* __restrict__ pcMax,
                                             float* __restrict__ ubNN, float* __restrict__ ubRep,
                                             u32* __restrict__ ubCNN, u32* __restrict__ ubCRep,
                                             u64* __restrict__ keys, u32* __restrict__ repmax) {
    const int b = blockIdx.x;
    const int tid = threadIdx.x;

    if (b < 416 && b >= 352 + 64) {
        // unreachable (grid is 416); placate nothing
    }

    if (b < 256 || (b >= 256 && b < 352)) {
        // ---- bounds blocks ----
        __shared__ float mn[256], mx[256];
        float z;
        if (b < 256) {                    // gt tile b
            z = (tid < GT_TPS) ? sGt[b * GT_TPS + tid].z : 0.0f;
            if (tid >= GT_TPS) { mn[tid] = 3e38f; mx[tid] = -3e38f; }
            else { mn[tid] = z; mx[tid] = z; }
        } else if (b < 288) {             // pred chunk c = b-256
            z = sPr[(b - 256) * CHN + tid].z;
            mn[tid] = z; mx[tid] = z;
        } else {                          // pred tile t = b-288
            z = (tid < PR_TPS) ? sPr[(b - 288) * PR_TPS + tid].z : 0.0f;
            if (tid >= PR_TPS) { mn[tid] = 3e38f; mx[tid] = -3e38f; }
            else { mn[tid] = z; mx[tid] = z; }
        }
        __syncthreads();
        for (int s = 128; s > 0; s >>= 1) {
            if (tid < s) {
                mn[tid] = fminf(mn[tid], mn[tid + s]);
                mx[tid] = fmaxf(mx[tid], mx[tid + s]);
            }
            __syncthreads();
        }
        if (tid == 0) {
            if (b < 256) { gtTmin[b] = mn[0]; gtTmax[b] = mx[0]; }
            else if (b < 288) { pcMin[b - 256] = mn[0]; pcMax[b - 256] = mx[0]; }
            else { prTmin[b - 288] = mn[0]; prTmax[b - 288] = mx[0]; }
        }
    } else if (b < 384) {
        // ---- phase A, NN: s = (b-352)*256 + tid ----
        const int s = (b - 352) * 256 + tid;
        const v4f P = sPr[s];
        const float px = P.x, py = P.y, pz = P.z;
        const float pp2 = px * px + py * py + pz * pz;
        int t0 = (int)(gtStart[zbin(pz)] >> 7);
        t0 = t0 > GT_NT - 1 ? GT_NT - 1 : t0;
        t0 = __builtin_amdgcn_readfirstlane(t0);
        const int lo = t0 - 1 < 0 ? 0 : t0 - 1;
        const int hi = t0 + 2 > GT_NT - 1 ? GT_NT - 1 : t0 + 2;
        float bh = 0.0f; u32 bpos = 0u;
        for (int t = lo; t <= hi; ++t) {
#pragma unroll 4
            for (int k = 0; k < GT_TPS; ++k) {
                const v4f g = sGt[t * GT_TPS + k];
                const float h = fmaf(px, g.x, fmaf(py, g.y, fmaf(pz, g.z, g.w)));
                if (h > bh) { bh = h; bpos = (u32)(t * GT_TPS + k); }
            }
        }
        float d2 = fmaf(-2.0f, bh, pp2 + 2.0f * HOFF);
        d2 = fmaxf(d2, 0.0f);
        const float ub = sqrtf(d2);
        ubNN[s] = ub;
        atomicMax(&ubCNN[s >> 8], __float_as_uint(ub));
        const u64 key = ((u64)__float_as_uint(bh) << 32) | (u64)(~bpos);
        atomicMax(&keys[s], key);
    } else {
        // ---- phase A, REP: s = (b-384)*256 + tid ----
        const int s = (b - 384) * 256 + tid;
        const v4f P = sPr[s];
        const float px = P.x, py = P.y, pz = P.z;
        const float pp2 = px * px + py * py + pz * pz;
        int u0 = (int)(prStart[zbin(pz)] >> 7);
        u0 = u0 > PR_NT - 1 ? PR_NT - 1 : u0;
        u0 = __builtin_amdgcn_readfirstlane(u0);
        const int lo = u0 - 1 < 0 ? 0 : u0 - 1;
        const int hi = u0 + 1 > PR_NT - 1 ? PR_NT - 1 : u0 + 1;
        float bh = 0.0f;
        for (int t = lo; t <= hi; ++t) {
#pragma unroll 4
            for (int k = 0; k < PR_TPS; ++k) {
                const int pos = t * PR_TPS + k;
                const v4f g = sPr[pos];
                float h = fmaf(px, g.x, fmaf(py, g.y, fmaf(pz, g.z, g.w)));
                h = (pos == s) ? 0.0f : h;          // exclude self (real h > 34)
                bh = fmaxf(bh, h);
            }
        }
        atomicMax(&repmax[s], __float_as_uint(bh));
        float d2 = fmaf(-2.0f, bh, pp2 + 2.0f * HOFF);
        d2 = fmaxf(d2, 0.0f);
        const float ub = sqrtf(d2);
        ubRep[s] = ub;
        atomicMax(&ubCRep[s >> 8], __float_as_uint(ub));
    }
}

// ---- phase B: windowed exact scans with provable skips ----
__global__ __launch_bounds__(256) void k_pairB(const v4f* __restrict__ sGt,
                                               const v4f* __restrict__ sPr,
                                               const float* __restrict__ gtTmin, const float* __restrict__ gtTmax,
                                               const float* __restrict__ prTmin, const float* __restrict__ prTmax,
                                               const float* __restrict__ pcMin, const float* __restrict__ pcMax,
                                               const float* __restrict__ ubNN, const float* __restrict__ ubRep,
                                               const u32* __restrict__ ubCNN, const u32* __restrict__ ubCRep,
                                               u64* __restrict__ keys, u32* __restrict__ repmax) {
    const int bid = blockIdx.x;
    if (bid < NCH * GT_NT) {
        // ---- NN: chunk c vs gt tile t ----
        const int c = bid >> 8;                  // / GT_NT
        const int t = bid & (GT_NT - 1);
        const float tzmin = gtTmin[t], tzmax = gtTmax[t];
        const float gapc = fmaxf(0.0f, fmaxf(tzmin - pcMax[c], pcMin[c] - tzmax));
        if (gapc > __uint_as_float(ubCNN[c])) return;     // block-uniform skip

        const int s = c * CHN + threadIdx.x;
        const v4f P = sPr[s];
        const float gapp = fmaxf(0.0f, fmaxf(tzmin - P.z, P.z - tzmax));
        if (gapp <= ubNN[s]) {
            const float px = P.x, py = P.y, pz = P.z;
            float bh = 0.0f; u32 bpos = 0u;
            const int base = t * GT_TPS;
#pragma unroll 4
            for (int k = 0; k < GT_TPS; ++k) {
                const v4f g = sGt[base + k];
                const float h = fmaf(px, g.x, fmaf(py, g.y, fmaf(pz, g.z, g.w)));
                if (h > bh) { bh = h; bpos = (u32)(base + k); }
            }
            const u64 key = ((u64)__float_as_uint(bh) << 32) | (u64)(~bpos);
            atomicMax(&keys[s], key);
        }
    } else {
        // ---- REP: chunk c vs pred tile t ----
        const int rb = bid - NCH * GT_NT;
        const int c = rb >> 6;                   // / PR_NT
        const int t = rb & (PR_NT - 1);
        const float tzmin = prTmin[t], tzmax = prTmax[t];
        const float gapc = fmaxf(0.0f, fmaxf(tzmin - pcMax[c], pcMin[c] - tzmax));
        if (gapc > __uint_as_float(ubCRep[c])) return;

        const int s = c * CHN + threadIdx.x;
        const v4f P = sPr[s];
        const float gapp = fmaxf(0.0f, fmaxf(tzmin - P.z, P.z - tzmax));
        if (gapp <= ubRep[s]) {
            const float px = P.x, py = P.y, pz = P.z;
            float bh = 0.0f;
            const int base = t * PR_TPS;
#pragma unroll 4
            for (int k = 0; k < PR_TPS; ++k) {
                const int pos = base + k;
                const v4f g = sPr[pos];
                float h = fmaf(px, g.x, fmaf(py, g.y, fmaf(pz, g.z, g.w)));
                h = (pos == s) ? 0.0f : h;
                bh = fmaxf(bh, h);
            }
            atomicMax(&repmax[s], __float_as_uint(bh));
        }
    }
}

// ---- finalize: per sorted pred, losses; block partials ----
__global__ __launch_bounds__(256) void k_fin(const float* __restrict__ pred,
                                             const float* __restrict__ gt,
                                             const u64* __restrict__ keys,
                                             const u32* __restrict__ repmax,
                                             const u32* __restrict__ sGtIdx,
                                             const u32* __restrict__ sPrIdx,
                                             float* __restrict__ partials) {
    const int s = blockIdx.x * 256 + threadIdx.x;
    const u64 key = keys[s];
    const u32 pos = ~(u32)(key & 0xFFFFFFFFull);
    const int j = (int)sGtIdx[pos];
    const int p = (int)sPrIdx[s];

    const float px = pred[p * 6 + 0], py = pred[p * 6 + 1], pz = pred[p * 6 + 2];
    const float gx = gt[j * 6 + 0],  gy = gt[j * 6 + 1],  gz = gt[j * 6 + 2];
    const float dx = px - gx, dy = py - gy, dz = pz - gz;
    float att = dx * dx + dy * dy + dz * dz;

    const float pnx = pred[p * 6 + 3], pny = pred[p * 6 + 4], pnz = pred[p * 6 + 5];
    const float gnx = gt[j * 6 + 3],   gny = gt[j * 6 + 4],   gnz = gt[j * 6 + 5];
    const float pl = fmaxf(sqrtf(pnx * pnx + pny * pny + pnz * pnz), 1e-5f);
    const float gl = fmaxf(sqrtf(gnx * gnx + gny * gny + gnz * gnz), 1e-5f);
    float nrm = 1.0f - (pnx * gnx + pny * gny + pnz * gnz) / (pl * gl);

    const float h = __uint_as_float(repmax[s]);
    const float pp2 = px * px + py * py + pz * pz;
    float d2 = fmaf(-2.0f, h, pp2 + 2.0f * HOFF);
    d2 = fmaxf(d2, 0.0f);
    const float xa = 100.0f * (0.3f - sqrtf(d2));
    const float sp = fmaxf(xa, 0.0f) + log1pf(expf(-fabsf(xa)));
    float rep = sp * sp;

#pragma unroll
    for (int off = 32; off > 0; off >>= 1) {
        att += __shfl_down(att, off, 64);
        nrm += __shfl_down(nrm, off, 64);
        rep += __shfl_down(rep, off, 64);
    }
    __shared__ float red[4][3];
    const int wave = threadIdx.x >> 6;
    const int lane = threadIdx.x & 63;
    if (lane == 0) { red[wave][0] = att; red[wave][1] = nrm; red[wave][2] = rep; }
    __syncthreads();
    if (threadIdx.x < 3)
        partials[blockIdx.x * 3 + threadIdx.x] =
            red[0][threadIdx.x] + red[1][threadIdx.x] +
            red[2][threadIdx.x] + red[3][threadIdx.x];
}

__global__ void k_comb(const float* __restrict__ partials, float* __restrict__ out) {
    const int lane = threadIdx.x;                // 64 threads, 32 rows
    float a = 0.f, n = 0.f, r = 0.f;
    if (lane < NCH) {
        a = partials[lane * 3 + 0];
        n = partials[lane * 3 + 1];
        r = partials[lane * 3 + 2];
    }
#pragma unroll
    for (int off = 32; off > 0; off >>= 1) {
        a += __shfl_down(a, off, 64);
        n += __shfl_down(n, off, 64);
        r += __shfl_down(r, off, 64);
    }
    if (lane == 0)
        out[0] = a / (float)(N_PRED * 3) + r / (float)N_PRED + 10.0f * (n / (float)N_PRED);
}

extern "C" void kernel_launch(void* const* d_in, const int* in_sizes, int n_in,
                              void* d_out, int out_size, void* d_ws, size_t ws_size,
                              hipStream_t stream) {
    const float* pred = (const float*)d_in[0];   // (8192, 6)
    const float* gt   = (const float*)d_in[3];   // (32768, 6)
    float* out = (float*)d_out;
    char* ws = (char*)d_ws;

    u32* gtCount = (u32*)(ws + O_GTCNT);
    u32* prCount = (u32*)(ws + O_PRCNT);
    u32* gtCursor = (u32*)(ws + O_GTCUR);
    u32* prCursor = (u32*)(ws + O_PRCUR);
    u32* ubCNN = (u32*)(ws + O_UBCNN);
    u32* ubCRep = (u32*)(ws + O_UBCRP);
    u64* keys = (u64*)(ws + O_KEYS);
    u32* repmax = (u32*)(ws + O_REPMX);
    u32* gtStart = (u32*)(ws + O_GTSTART);
    u32* prStart = (u32*)(ws + O_PRSTART);
    v4f* sGt = (v4f*)(ws + O_SGT);
    u32* sGtIdx = (u32*)(ws + O_SGTIDX);
    v4f* sPr = (v4f*)(ws + O_SPR);
    u32* sPrIdx = (u32*)(ws + O_SPRIDX);
    float* ubNN = (float*)(ws + O_UBNN);
    float* ubRep = (float*)(ws + O_UBREP);
    float* gtTmin = (float*)(ws + O_GTTMIN);
    float* gtTmax = (float*)(ws + O_GTTMAX);
    float* prTmin = (float*)(ws + O_PRTMIN);
    float* prTmax = (float*)(ws + O_PRTMAX);
    float* pcMin = (float*)(ws + O_PCMIN);
    float* pcMax = (float*)(ws + O_PCMAX);
    float* partials = (float*)(ws + O_PART);

    hipMemsetAsync(ws, 0, MEMSET_BYTES, stream);
    k_count<<<128, 256, 0, stream>>>(pred, gt, gtCount, prCount);
    k_scan<<<1, 512, 0, stream>>>(gtCount, prCount, gtStart, prStart, gtCursor, prCursor);
    k_scatter<<<128, 256, 0, stream>>>(pred, gt, gtCursor, prCursor, sGt, sGtIdx, sPr, sPrIdx);
    k_mid<<<416, 256, 0, stream>>>(sGt, sPr, gtStart, prStart,
                                   gtTmin, gtTmax, prTmin, prTmax, pcMin, pcMax,
                                   ubNN, ubRep, ubCNN, ubCRep, keys, repmax);
    k_pairB<<<NCH * GT_NT + NCH * PR_NT, 256, 0, stream>>>(sGt, sPr,
                                   gtTmin, gtTmax, prTmin, prTmax, pcMin, pcMax,
                                   ubNN, ubRep, ubCNN, ubCRep, keys, repmax);
    k_fin<<<NCH, 256, 0, stream>>>(pred, gt, keys, repmax, sGtIdx, sPrIdx, partials);
    k_comb<<<1, 64, 0, stream>>>(partials, out);
}

// Round 10
// 50.190 us; speedup vs baseline: 4.0444x; 4.0444x over previous
//
#include <hip/hip_runtime.h>
#include <cstdint>

typedef unsigned short ushort_t;
typedef unsigned int u32;
typedef __attribute__((ext_vector_type(8))) short bf16x8;
typedef __attribute__((ext_vector_type(4))) float f32x4;

#define N_PRED 8192
#define N_GT   32768

// pair geometry: wave = 128 preds (8 B-frags) x 512-point target split (32 tiles)
// NN: 64 pred-groups x 64 splits = 4096 waves; REP: 64 x 16 = 1024 waves
#define NN_WAVES 4096
#define ALL_WAVES 5120

// ws: gtA 1MB | prA 256K | prB 256K | chunkNN[8192][64] 2MB | chunkRP[8192][16] 512K | partials
#define O_PRA   1048576u
#define O_PRB   (O_PRA + 262144u)
#define O_CNN   (O_PRB + 262144u)
#define O_CRP   (O_CNN + 2097152u)
#define O_PART  (O_CRP + 524288u)

__device__ __forceinline__ float max3f(float a, float b, float c) {
    float d;
    asm("v_max3_f32 %0, %1, %2, %3" : "=v"(d) : "v"(a), "v"(b), "v"(c));
    return d;
}
__device__ __forceinline__ ushort_t f2b(float v) {   // round-to-nearest-even bf16
    u32 b = __float_as_uint(v);
    return (ushort_t)((b + 0x7FFFu + ((b >> 16) & 1u)) >> 16);
}

// ---- prep: pack bf16 hi/lo fragment arrays (fragment-ordered, 32B/point) ----
// target form (A): g0=[xh,yh,zh,xh,yh,zh,xl,yl] g1=[zl,wh,wl,0...]  (w = -0.5|g|^2)
// query  form (B): g0=[xh,yh,zh,xl,yl,zl,xh,yh] g1=[zh,1,1,0...]
__global__ __launch_bounds__(256) void k_prep(const float* __restrict__ pred,
                                              const float* __restrict__ gt,
                                              ushort_t* __restrict__ gtA,
                                              ushort_t* __restrict__ prA,
                                              ushort_t* __restrict__ prB) {
    const int i = blockIdx.x * 256 + threadIdx.x;
    if (i < N_GT) {
        const float x = gt[i * 6 + 0], y = gt[i * 6 + 1], z = gt[i * 6 + 2];
        const ushort_t xh = f2b(x), yh = f2b(y), zh = f2b(z);
        const float xhf = __uint_as_float((u32)xh << 16);
        const float yhf = __uint_as_float((u32)yh << 16);
        const float zhf = __uint_as_float((u32)zh << 16);
        const ushort_t xl = f2b(x - xhf), yl = f2b(y - yhf), zl = f2b(z - zhf);
        const float w = -0.5f * fmaf(z, z, fmaf(y, y, x * x));
        const ushort_t wh = f2b(w);
        const ushort_t wl = f2b(w - __uint_as_float((u32)wh << 16));
        ushort_t* d = gtA + (i >> 4) * 256 + (i & 15) * 8;
        d[0] = xh; d[1] = yh; d[2] = zh; d[3] = xh; d[4] = yh; d[5] = zh; d[6] = xl; d[7] = yl;
        d += 128;
        d[0] = zl; d[1] = wh; d[2] = wl; d[3] = 0; d[4] = 0; d[5] = 0; d[6] = 0; d[7] = 0;
    }
    if (i < N_PRED) {
        const float x = pred[i * 6 + 0], y = pred[i * 6 + 1], z = pred[i * 6 + 2];
        const ushort_t xh = f2b(x), yh = f2b(y), zh = f2b(z);
        const float xhf = __uint_as_float((u32)xh << 16);
        const float yhf = __uint_as_float((u32)yh << 16);
        const float zhf = __uint_as_float((u32)zh << 16);
        const ushort_t xl = f2b(x - xhf), yl = f2b(y - yhf), zl = f2b(z - zhf);
        const float w = -0.5f * fmaf(z, z, fmaf(y, y, x * x));
        const ushort_t wh = f2b(w);
        const ushort_t wl = f2b(w - __uint_as_float((u32)wh << 16));
        ushort_t* a = prA + (i >> 4) * 256 + (i & 15) * 8;
        a[0] = xh; a[1] = yh; a[2] = zh; a[3] = xh; a[4] = yh; a[5] = zh; a[6] = xl; a[7] = yl;
        a += 128;
        a[0] = zl; a[1] = wh; a[2] = wl; a[3] = 0; a[4] = 0; a[5] = 0; a[6] = 0; a[7] = 0;
        const ushort_t ONE = 0x3F80;
        ushort_t* b = prB + (i >> 4) * 256 + (i & 15) * 8;
        b[0] = xh; b[1] = yh; b[2] = zh; b[3] = xl; b[4] = yl; b[5] = zl; b[6] = xh; b[7] = yh;
        b += 128;
        b[0] = zh; b[1] = ONE; b[2] = ONE; b[3] = 0; b[4] = 0; b[5] = 0; b[6] = 0; b[7] = 0;
    }
}

// ---- pair: MFMA bulk max. D[gt_row, pred_col] = h~. Per wave: 8 B-frags in regs,
//      32 A-tiles streamed, 8 MFMA + 16 max3 per tile. No LDS, no atomics. ----
__global__ __launch_bounds__(256) void k_pair(const ushort_t* __restrict__ gtA,
                                              const ushort_t* __restrict__ prA,
                                              const ushort_t* __restrict__ prB,
                                              float* __restrict__ chunkNN,
                                              float* __restrict__ chunkRP) {
    const int wid = blockIdx.x * 4 + (threadIdx.x >> 6);
    const int lane = threadIdx.x & 63;
    const bf16x8 z8 = {};
    const f32x4 zc = {};

    const bool isNN = (wid < NN_WAVES);
    const int rw = isNN ? wid : (wid - NN_WAVES);
    const int pg = rw & 63;            // pred group of 128
    const int sp = rw >> 6;            // target split of 512

    // B fragments: 8 groups of 16 preds (query form)
    const bf16x8* bp = (const bf16x8*)prB;
    bf16x8 B[8];
#pragma unroll
    for (int j = 0; j < 8; ++j) {
        B[j] = z8;
        if (lane < 32) B[j] = bp[(pg * 8 + j) * 32 + lane];
    }

    const bf16x8* ap = (const bf16x8*)(isNN ? gtA : prA) + sp * 1024 + lane;
    float best[8];
#pragma unroll
    for (int j = 0; j < 8; ++j) best[j] = -3.0e38f;

    const bool diagw = (!isNN) && (sp == (pg >> 2));
    if (!diagw) {
#pragma unroll 2
        for (int t = 0; t < 32; ++t) {
            bf16x8 A = z8;
            if (lane < 32) A = ap[t * 32];
#pragma unroll
            for (int j = 0; j < 8; ++j) {
                const f32x4 acc = __builtin_amdgcn_mfma_f32_16x16x32_bf16(A, B[j], zc, 0, 0, 0);
                best[j] = max3f(best[j], acc[0], acc[1]);
                best[j] = max3f(best[j], acc[2], acc[3]);
            }
        }
    } else {
        const int tb = 8 * (pg & 3);        // tiles tb..tb+7 are self-diagonal for j = t-tb
        const int col = lane & 15;
        const int r0 = (lane >> 4) * 4;
        for (int t = 0; t < 32; ++t) {
            bf16x8 A = z8;
            if (lane < 32) A = ap[t * 32];
#pragma unroll
            for (int j = 0; j < 8; ++j) {
                f32x4 acc = __builtin_amdgcn_mfma_f32_16x16x32_bf16(A, B[j], zc, 0, 0, 0);
                if (t == tb + j) {          // mask the self element (row==col)
                    acc[0] = (r0 + 0 == col) ? -3.0e38f : acc[0];
                    acc[1] = (r0 + 1 == col) ? -3.0e38f : acc[1];
                    acc[2] = (r0 + 2 == col) ? -3.0e38f : acc[2];
                    acc[3] = (r0 + 3 == col) ? -3.0e38f : acc[3];
                }
                best[j] = max3f(best[j], acc[0], acc[1]);
                best[j] = max3f(best[j], acc[2], acc[3]);
            }
        }
    }

    // merge the 4 row-quarters (lanes sharing a pred col): xor 16, 32
#pragma unroll
    for (int j = 0; j < 8; ++j) {
        best[j] = fmaxf(best[j], __shfl_xor(best[j], 16));
        best[j] = fmaxf(best[j], __shfl_xor(best[j], 32));
    }
    if (lane < 16) {
#pragma unroll
        for (int j = 0; j < 8; ++j) {
            const int P = pg * 128 + j * 16 + lane;
            if (isNN) chunkNN[P * 64 + sp] = best[j];
            else      chunkRP[P * 16 + sp] = best[j];
        }
    }
}

// ---- finalize: wave-per-pred; exact fp32 rescan of winning chunks; losses ----
__global__ __launch_bounds__(256) void k_fin(const float* __restrict__ pred,
                                             const float* __restrict__ gt,
                                             const float* __restrict__ chunkNN,
                                             const float* __restrict__ chunkRP,
                                             float* __restrict__ partials) {
    const int wave = threadIdx.x >> 6;
    const int lane = threadIdx.x & 63;
    const int p = blockIdx.x * 4 + wave;

    const float px = pred[p * 6 + 0], py = pred[p * 6 + 1], pz = pred[p * 6 + 2];

    // --- NN: argmax chunk over 64 approx maxes (tie -> smaller chunk) ---
    float m = chunkNN[p * 64 + lane];
    int c = lane;
#pragma unroll
    for (int off = 32; off > 0; off >>= 1) {
        const float om = __shfl_xor(m, off);
        const int   oc = __shfl_xor(c, off);
        const bool take = (om > m) || (om == m && oc < c);
        m = take ? om : m;
        c = take ? oc : c;
    }
    // exact rescan of 512-gt chunk (fp32; ties -> smallest gt index)
    float bh = -3.0e38f;
    int bj = 0x7FFFFFFF;
#pragma unroll 2
    for (int i = 0; i < 8; ++i) {
        const int g = c * 512 + i * 64 + lane;
        const float x = gt[g * 6 + 0], y = gt[g * 6 + 1], z = gt[g * 6 + 2];
        const float w = -0.5f * fmaf(z, z, fmaf(y, y, x * x));
        const float h = fmaf(px, x, fmaf(py, y, fmaf(pz, z, w)));
        if (h > bh) { bh = h; bj = g; }
    }
#pragma unroll
    for (int off = 32; off > 0; off >>= 1) {
        const float oh = __shfl_xor(bh, off);
        const int   og = __shfl_xor(bj, off);
        const bool take = (oh > bh) || (oh == bh && og < bj);
        bh = take ? oh : bh;
        bj = take ? og : bj;
    }
    const int j = bj;

    // --- REP: argmax chunk over 16 approx maxes, exact rescan (value only) ---
    float rm = (lane < 16) ? chunkRP[p * 16 + lane] : -3.0e38f;
    int rc = (lane < 16) ? lane : 0;
#pragma unroll
    for (int off = 32; off > 0; off >>= 1) {
        const float om = __shfl_xor(rm, off);
        const int   oc = __shfl_xor(rc, off);
        const bool take = (om > rm) || (om == rm && oc < rc);
        rm = take ? om : rm;
        rc = take ? oc : rc;
    }
    float hr = -3.0e38f;
#pragma unroll 2
    for (int i = 0; i < 8; ++i) {
        const int q = rc * 512 + i * 64 + lane;
        const float x = pred[q * 6 + 0], y = pred[q * 6 + 1], z = pred[q * 6 + 2];
        const float w = -0.5f * fmaf(z, z, fmaf(y, y, x * x));
        float h = fmaf(px, x, fmaf(py, y, fmaf(pz, z, w)));
        h = (q == p) ? -3.0e38f : h;
        hr = fmaxf(hr, h);
    }
#pragma unroll
    for (int off = 32; off > 0; off >>= 1) hr = fmaxf(hr, __shfl_xor(hr, off));

    __shared__ float red[4][3];
    if (lane == 0) {
        const float gx = gt[j * 6 + 0], gy = gt[j * 6 + 1], gz = gt[j * 6 + 2];
        const float dx = px - gx, dy = py - gy, dz = pz - gz;
        const float att = dx * dx + dy * dy + dz * dz;

        const float pnx = pred[p * 6 + 3], pny = pred[p * 6 + 4], pnz = pred[p * 6 + 5];
        const float gnx = gt[j * 6 + 3],   gny = gt[j * 6 + 4],   gnz = gt[j * 6 + 5];
        const float pl = fmaxf(sqrtf(pnx * pnx + pny * pny + pnz * pnz), 1e-5f);
        const float gl = fmaxf(sqrtf(gnx * gnx + gny * gny + gnz * gnz), 1e-5f);
        const float nrm = 1.0f - (pnx * gnx + pny * gny + pnz * gnz) / (pl * gl);

        const float pp2 = px * px + py * py + pz * pz;
        float d2 = fmaf(-2.0f, hr, pp2);
        d2 = fmaxf(d2, 0.0f);
        const float xa = 100.0f * (0.3f - sqrtf(d2));
        const float sp2 = fmaxf(xa, 0.0f) + log1pf(expf(-fabsf(xa)));

        red[wave][0] = att;
        red[wave][1] = nrm;
        red[wave][2] = sp2 * sp2;
    }
    __syncthreads();
    if (threadIdx.x < 3)
        partials[blockIdx.x * 3 + threadIdx.x] =
            red[0][threadIdx.x] + red[1][threadIdx.x] +
            red[2][threadIdx.x] + red[3][threadIdx.x];
}

__device__ __forceinline__ float wave_reduce(float v) {
#pragma unroll
    for (int off = 32; off > 0; off >>= 1) v += __shfl_down(v, off, 64);
    return v;
}

__global__ __launch_bounds__(256) void k_comb(const float* __restrict__ partials,
                                              float* __restrict__ out) {
    float a = 0.f, n = 0.f, r = 0.f;
    const int t = threadIdx.x;
#pragma unroll
    for (int k = 0; k < 8; ++k) {
        const int row = t + k * 256;          // 2048 rows
        a += partials[row * 3 + 0];
        n += partials[row * 3 + 1];
        r += partials[row * 3 + 2];
    }
    a = wave_reduce(a);
    n = wave_reduce(n);
    r = wave_reduce(r);
    __shared__ float red[3][4];
    const int wave = t >> 6, lane = t & 63;
    if (lane == 0) { red[0][wave] = a; red[1][wave] = n; red[2][wave] = r; }
    __syncthreads();
    if (t == 0) {
        const float A = red[0][0] + red[0][1] + red[0][2] + red[0][3];
        const float Nn = red[1][0] + red[1][1] + red[1][2] + red[1][3];
        const float R = red[2][0] + red[2][1] + red[2][2] + red[2][3];
        out[0] = A / (float)(N_PRED * 3) + R / (float)N_PRED + 10.0f * (Nn / (float)N_PRED);
    }
}

extern "C" void kernel_launch(void* const* d_in, const int* in_sizes, int n_in,
                              void* d_out, int out_size, void* d_ws, size_t ws_size,
                              hipStream_t stream) {
    const float* pred = (const float*)d_in[0];   // (8192, 6)
    const float* gt   = (const float*)d_in[3];   // (32768, 6)
    float* out = (float*)d_out;
    char* ws = (char*)d_ws;

    ushort_t* gtA = (ushort_t*)ws;
    ushort_t* prA = (ushort_t*)(ws + O_PRA);
    ushort_t* prB = (ushort_t*)(ws + O_PRB);
    float* chunkNN = (float*)(ws + O_CNN);
    float* chunkRP = (float*)(ws + O_CRP);
    float* partials = (float*)(ws + O_PART);

    k_prep<<<N_GT / 256, 256, 0, stream>>>(pred, gt, gtA, prA, prB);
    k_pair<<<ALL_WAVES / 4, 256, 0, stream>>>(gtA, prA, prB, chunkNN, chunkRP);
    k_fin<<<N_PRED / 4, 256, 0, stream>>>(pred, gt, chunkNN, chunkRP, partials);
    k_comb<<<1, 256, 0, stream>>>(partials, out);
}

// Round 11
// 38.864 us; speedup vs baseline: 5.2230x; 1.2914x over previous
//
#include <hip/hip_runtime.h>
#include <cstdint>

typedef unsigned short ushort_t;
typedef unsigned int u32;
typedef __attribute__((ext_vector_type(8))) short bf16x8;
typedef __attribute__((ext_vector_type(16))) float f32x16;

#define N_PRED 8192
#define N_GT   32768

// wave = 128 preds (4 B-frags of 32) x 512 targets (16 A-tiles of 32)
// NN: 64 pred-groups x 64 splits = 4096 waves; REP: 64 x 16 = 1024
#define NN_WAVES  4096
#define ALL_WAVES 5120

// ws: gtA 1MB | prA 256K | prB 256K | chunkNN[8192][64] 2MB | chunkRP[8192][16] 512K | partials
#define O_PRA  1048576u
#define O_PRB  1310720u
#define O_CNN  1572864u
#define O_CRP  3670016u
#define O_PART 4194304u

__device__ __forceinline__ float max3f(float a, float b, float c) {
    float d;
    asm("v_max3_f32 %0, %1, %2, %3" : "=v"(d) : "v"(a), "v"(b), "v"(c));
    return d;
}
__device__ __forceinline__ ushort_t f2b(float v) {   // round-to-nearest-even bf16
    u32 b = __float_as_uint(v);
    return (ushort_t)((b + 0x7FFFu + ((b >> 16) & 1u)) >> 16);
}
// max of 16 accs folded into best (8 x v_max3)
__device__ __forceinline__ float red16(const f32x16 a, float best) {
    const float m0 = max3f(a[0], a[1], a[2]);
    const float m1 = max3f(a[3], a[4], a[5]);
    const float m2 = max3f(a[6], a[7], a[8]);
    const float m3 = max3f(a[9], a[10], a[11]);
    const float m4 = max3f(a[12], a[13], a[14]);
    const float m5 = max3f(m0, m1, a[15]);
    const float m6 = max3f(m2, m3, m4);
    return max3f(best, m5, m6);
}

// ---- prep: pack bf16 hi/lo fragments, 32-row groups (row=lane&31, k-half=lane>>5)
// A (target): k0-7=[xh,yh,zh,xh,yh,zh,xl,yl]  k8-15=[zl,wh,wl,0...]  (w=-0.5|g|^2)
// B (query) : k0-7=[xh,yh,zh,xl,yl,zl,xh,yh]  k8-15=[zh,1,1,0...]
__global__ __launch_bounds__(256) void k_prep(const float* __restrict__ pred,
                                              const float* __restrict__ gt,
                                              ushort_t* __restrict__ gtA,
                                              ushort_t* __restrict__ prA,
                                              ushort_t* __restrict__ prB) {
    const int i = blockIdx.x * 256 + threadIdx.x;
    if (i < N_GT) {
        const float x = gt[i * 6 + 0], y = gt[i * 6 + 1], z = gt[i * 6 + 2];
        const ushort_t xh = f2b(x), yh = f2b(y), zh = f2b(z);
        const ushort_t xl = f2b(x - __uint_as_float((u32)xh << 16));
        const ushort_t yl = f2b(y - __uint_as_float((u32)yh << 16));
        const ushort_t zl = f2b(z - __uint_as_float((u32)zh << 16));
        const float w = -0.5f * fmaf(z, z, fmaf(y, y, x * x));
        const ushort_t wh = f2b(w);
        const ushort_t wl = f2b(w - __uint_as_float((u32)wh << 16));
        ushort_t* d = gtA + (i >> 5) * 512 + (i & 31) * 8;
        d[0] = xh; d[1] = yh; d[2] = zh; d[3] = xh; d[4] = yh; d[5] = zh; d[6] = xl; d[7] = yl;
        d += 256;
        d[0] = zl; d[1] = wh; d[2] = wl; d[3] = 0; d[4] = 0; d[5] = 0; d[6] = 0; d[7] = 0;
    }
    if (i < N_PRED) {
        const float x = pred[i * 6 + 0], y = pred[i * 6 + 1], z = pred[i * 6 + 2];
        const ushort_t xh = f2b(x), yh = f2b(y), zh = f2b(z);
        const ushort_t xl = f2b(x - __uint_as_float((u32)xh << 16));
        const ushort_t yl = f2b(y - __uint_as_float((u32)yh << 16));
        const ushort_t zl = f2b(z - __uint_as_float((u32)zh << 16));
        const float w = -0.5f * fmaf(z, z, fmaf(y, y, x * x));
        const ushort_t wh = f2b(w);
        const ushort_t wl = f2b(w - __uint_as_float((u32)wh << 16));
        ushort_t* a = prA + (i >> 5) * 512 + (i & 31) * 8;
        a[0] = xh; a[1] = yh; a[2] = zh; a[3] = xh; a[4] = yh; a[5] = zh; a[6] = xl; a[7] = yl;
        a += 256;
        a[0] = zl; a[1] = wh; a[2] = wl; a[3] = 0; a[4] = 0; a[5] = 0; a[6] = 0; a[7] = 0;
        const ushort_t ONE = 0x3F80;
        ushort_t* b = prB + (i >> 5) * 512 + (i & 31) * 8;
        b[0] = xh; b[1] = yh; b[2] = zh; b[3] = xl; b[4] = yl; b[5] = zl; b[6] = xh; b[7] = yh;
        b += 256;
        b[0] = zh; b[1] = ONE; b[2] = ONE; b[3] = 0; b[4] = 0; b[5] = 0; b[6] = 0; b[7] = 0;
    }
}

// ---- pair: 32x32x16 MFMA bulk max, branch-free, A double-buffered ----
__global__ __launch_bounds__(256) void k_pair(const ushort_t* __restrict__ gtA,
                                              const ushort_t* __restrict__ prA,
                                              const ushort_t* __restrict__ prB,
                                              float* __restrict__ chunkNN,
                                              float* __restrict__ chunkRP) {
    const int wid = blockIdx.x * 4 + (threadIdx.x >> 6);
    const int lane = threadIdx.x & 63;
    const f32x16 zc = {};

    const bool isNN = (wid < NN_WAVES);
    const int rw = isNN ? wid : (wid - NN_WAVES);
    const int pg = rw & 63;            // pred group of 128
    const int sp = rw >> 6;            // target split of 512

    const int lu = (lane >> 5) * 32 + (lane & 31);    // unit offset within a 32-row group

    const bf16x8* bp = (const bf16x8*)prB;
    const bf16x8 B0 = bp[(pg * 4 + 0) * 64 + lu];
    const bf16x8 B1 = bp[(pg * 4 + 1) * 64 + lu];
    const bf16x8 B2 = bp[(pg * 4 + 2) * 64 + lu];
    const bf16x8 B3 = bp[(pg * 4 + 3) * 64 + lu];

    const bf16x8* a0 = (const bf16x8*)(isNN ? gtA : prA) + sp * 1024 + lu;

    float b0 = -3.0e38f, b1 = -3.0e38f, b2 = -3.0e38f, b3 = -3.0e38f;
    bf16x8 Acur = a0[0];
#pragma unroll
    for (int t = 0; t < 16; ++t) {
        const bf16x8 Anxt = (t < 15) ? a0[(t + 1) * 64] : Acur;
        f32x16 accA = __builtin_amdgcn_mfma_f32_32x32x16_bf16(Acur, B0, zc, 0, 0, 0);
        f32x16 accB = __builtin_amdgcn_mfma_f32_32x32x16_bf16(Acur, B1, zc, 0, 0, 0);
        b0 = red16(accA, b0);
        accA = __builtin_amdgcn_mfma_f32_32x32x16_bf16(Acur, B2, zc, 0, 0, 0);
        b1 = red16(accB, b1);
        accB = __builtin_amdgcn_mfma_f32_32x32x16_bf16(Acur, B3, zc, 0, 0, 0);
        b2 = red16(accA, b2);
        b3 = red16(accB, b3);
        Acur = Anxt;
    }

    // merge the two row-halves (lane, lane^32 share a pred col)
    b0 = fmaxf(b0, __shfl_xor(b0, 32));
    b1 = fmaxf(b1, __shfl_xor(b1, 32));
    b2 = fmaxf(b2, __shfl_xor(b2, 32));
    b3 = fmaxf(b3, __shfl_xor(b3, 32));

    if (lane < 32) {
        const int Pb = pg * 128 + lane;
        if (isNN) {
            chunkNN[(Pb +  0) * 64 + sp] = b0;
            chunkNN[(Pb + 32) * 64 + sp] = b1;
            chunkNN[(Pb + 64) * 64 + sp] = b2;
            chunkNN[(Pb + 96) * 64 + sp] = b3;
        } else {
            chunkRP[(Pb +  0) * 16 + sp] = b0;
            chunkRP[(Pb + 32) * 16 + sp] = b1;
            chunkRP[(Pb + 64) * 16 + sp] = b2;
            chunkRP[(Pb + 96) * 16 + sp] = b3;
        }
    }
}

// ---- finalize: wave-per-pred; exact fp32 rescans; losses ----
__global__ __launch_bounds__(256) void k_fin(const float* __restrict__ pred,
                                             const float* __restrict__ gt,
                                             const float* __restrict__ chunkNN,
                                             const float* __restrict__ chunkRP,
                                             float* __restrict__ partials) {
    const int wave = threadIdx.x >> 6;
    const int lane = threadIdx.x & 63;
    const int p = blockIdx.x * 4 + wave;

    const float px = pred[p * 6 + 0], py = pred[p * 6 + 1], pz = pred[p * 6 + 2];

    // --- NN: argmax chunk over 64 approx maxes (tie -> smaller chunk) ---
    float m = chunkNN[p * 64 + lane];
    int c = lane;
#pragma unroll
    for (int off = 32; off > 0; off >>= 1) {
        const float om = __shfl_xor(m, off);
        const int   oc = __shfl_xor(c, off);
        const bool take = (om > m) || (om == m && oc < c);
        m = take ? om : m;
        c = take ? oc : c;
    }
    // exact rescan of 512-gt chunk (fp32; ties -> smallest gt index)
    float bh = -3.0e38f;
    int bj = 0x7FFFFFFF;
#pragma unroll 2
    for (int i = 0; i < 8; ++i) {
        const int g = c * 512 + i * 64 + lane;
        const float x = gt[g * 6 + 0], y = gt[g * 6 + 1], z = gt[g * 6 + 2];
        const float w = -0.5f * fmaf(z, z, fmaf(y, y, x * x));
        const float h = fmaf(px, x, fmaf(py, y, fmaf(pz, z, w)));
        if (h > bh) { bh = h; bj = g; }
    }
#pragma unroll
    for (int off = 32; off > 0; off >>= 1) {
        const float oh = __shfl_xor(bh, off);
        const int   og = __shfl_xor(bj, off);
        const bool take = (oh > bh) || (oh == bh && og < bj);
        bh = take ? oh : bh;
        bj = take ? og : bj;
    }
    const int j = bj;

    // --- REP: self chunk c1 (exact, excl self) + best non-self chunk c2 ---
    const int c1 = p >> 9;
    float rm = -3.0e38f;
    int rc = 0;
    if (lane < 16 && lane != c1) { rm = chunkRP[p * 16 + lane]; rc = lane; }
#pragma unroll
    for (int off = 32; off > 0; off >>= 1) {
        const float om = __shfl_xor(rm, off);
        const int   oc = __shfl_xor(rc, off);
        const bool take = (om > rm) || (om == rm && oc < rc);
        rm = take ? om : rm;
        rc = take ? oc : rc;
    }
    float hr = -3.0e38f;
#pragma unroll 2
    for (int i = 0; i < 8; ++i) {
        const int q = c1 * 512 + i * 64 + lane;
        const float x = pred[q * 6 + 0], y = pred[q * 6 + 1], z = pred[q * 6 + 2];
        const float w = -0.5f * fmaf(z, z, fmaf(y, y, x * x));
        float h = fmaf(px, x, fmaf(py, y, fmaf(pz, z, w)));
        h = (q == p) ? -3.0e38f : h;
        hr = fmaxf(hr, h);
    }
#pragma unroll 2
    for (int i = 0; i < 8; ++i) {
        const int q = rc * 512 + i * 64 + lane;
        const float x = pred[q * 6 + 0], y = pred[q * 6 + 1], z = pred[q * 6 + 2];
        const float w = -0.5f * fmaf(z, z, fmaf(y, y, x * x));
        float h = fmaf(px, x, fmaf(py, y, fmaf(pz, z, w)));
        h = (q == p) ? -3.0e38f : h;
        hr = fmaxf(hr, h);
    }
#pragma unroll
    for (int off = 32; off > 0; off >>= 1) hr = fmaxf(hr, __shfl_xor(hr, off));

    __shared__ float red[4][3];
    if (lane == 0) {
        const float gx = gt[j * 6 + 0], gy = gt[j * 6 + 1], gz = gt[j * 6 + 2];
        const float dx = px - gx, dy = py - gy, dz = pz - gz;
        const float att = dx * dx + dy * dy + dz * dz;

        const float pnx = pred[p * 6 + 3], pny = pred[p * 6 + 4], pnz = pred[p * 6 + 5];
        const float gnx = gt[j * 6 + 3],   gny = gt[j * 6 + 4],   gnz = gt[j * 6 + 5];
        const float pl = fmaxf(sqrtf(pnx * pnx + pny * pny + pnz * pnz), 1e-5f);
        const float gl = fmaxf(sqrtf(gnx * gnx + gny * gny + gnz * gnz), 1e-5f);
        const float nrm = 1.0f - (pnx * gnx + pny * gny + pnz * gnz) / (pl * gl);

        const float pp2 = px * px + py * py + pz * pz;
        float d2 = fmaf(-2.0f, hr, pp2);
        d2 = fmaxf(d2, 0.0f);
        const float xa = 100.0f * (0.3f - sqrtf(d2));
        const float sp2 = fmaxf(xa, 0.0f) + log1pf(expf(-fabsf(xa)));

        red[wave][0] = att;
        red[wave][1] = nrm;
        red[wave][2] = sp2 * sp2;
    }
    __syncthreads();
    if (threadIdx.x < 3)
        partials[blockIdx.x * 3 + threadIdx.x] =
            red[0][threadIdx.x] + red[1][threadIdx.x] +
            red[2][threadIdx.x] + red[3][threadIdx.x];
}

__device__ __forceinline__ float wave_reduce(float v) {
#pragma unroll
    for (int off = 32; off > 0; off >>= 1) v += __shfl_down(v, off, 64);
    return v;
}

__global__ __launch_bounds__(256) void k_comb(const float* __restrict__ partials,
                                              float* __restrict__ out) {
    float a = 0.f, n = 0.f, r = 0.f;
    const int t = threadIdx.x;
#pragma unroll
    for (int k = 0; k < 8; ++k) {
        const int row = t + k * 256;          // 2048 rows
        a += partials[row * 3 + 0];
        n += partials[row * 3 + 1];
        r += partials[row * 3 + 2];
    }
    a = wave_reduce(a);
    n = wave_reduce(n);
    r = wave_reduce(r);
    __shared__ float red[3][4];
    const int wave = t >> 6, lane = t & 63;
    if (lane == 0) { red[0][wave] = a; red[1][wave] = n; red[2][wave] = r; }
    __syncthreads();
    if (t == 0) {
        const float A = red[0][0] + red[0][1] + red[0][2] + red[0][3];
        const float Nn = red[1][0] + red[1][1] + red[1][2] + red[1][3];
        const float R = red[2][0] + red[2][1] + red[2][2] + red[2][3];
        out[0] = A / (float)(N_PRED * 3) + R / (float)N_PRED + 10.0f * (Nn / (float)N_PRED);
    }
}

extern "C" void kernel_launch(void* const* d_in, const int* in_sizes, int n_in,
                              void* d_out, int out_size, void* d_ws, size_t ws_size,
                              hipStream_t stream) {
    const float* pred = (const float*)d_in[0];   // (8192, 6)
    const float* gt   = (const float*)d_in[3];   // (32768, 6)
    float* out = (float*)d_out;
    char* ws = (char*)d_ws;

    ushort_t* gtA = (ushort_t*)ws;
    ushort_t* prA = (ushort_t*)(ws + O_PRA);
    ushort_t* prB = (ushort_t*)(ws + O_PRB);
    float* chunkNN = (float*)(ws + O_CNN);
    float* chunkRP = (float*)(ws + O_CRP);
    float* partials = (float*)(ws + O_PART);

    k_prep<<<N_GT / 256, 256, 0, stream>>>(pred, gt, gtA, prA, prB);
    k_pair<<<ALL_WAVES / 4, 256, 0, stream>>>(gtA, prA, prB, chunkNN, chunkRP);
    k_fin<<<N_PRED / 4, 256, 0, stream>>>(pred, gt, chunkNN, chunkRP, partials);
    k_comb<<<1, 256, 0, stream>>>(partials, out);
}